// Round 2
// baseline (425.364 us; speedup 1.0000x reference)
//
#include <hip/hip_runtime.h>

#define BN 128
#define DTCF 512
#define TT 1024
#define GAF 256
#define DKK 32
#define HID 64
#define NCLS 4
#define LNEPS 1e-5f
#define SCALE 0.17677669529663687f   // 1/sqrt(32)

typedef float f4v __attribute__((ext_vector_type(4)));

// ---------------------------------------------------------------------------
// Kernel 1: pass A, d-halved for full-GPU streaming. Grid (BN, 2), 1024 thr.
// Block (b,h) computes KV + its own 256-d slice of u/qv in-block, then
// streams tcf[b, h*256:(h+1)*256, :] with thread-owns-t scalar columns,
// emitting per-t partial (sx,sxx,sxu,sxq) -> 4 MB of partials total.
// ---------------------------------------------------------------------------
__global__ __launch_bounds__(1024) void k_A(
    const float* __restrict__ tcf, const float* __restrict__ gaf,
    const float* __restrict__ Wq, const float* __restrict__ Wkv,
    const float* __restrict__ Wout,
    float* __restrict__ u, float* __restrict__ part)
{
    int b = blockIdx.x, h = blockIdx.y, tid = threadIdx.x;

    __shared__ float gaf_s[GAF];
    __shared__ float kvp[DKK][8];
    __shared__ float kv_s[DKK];
    __shared__ float2 uq_s[256];         // .x = u[d], .y = qv[d] (this half)

    if (tid < GAF) gaf_s[tid] = gaf[b * GAF + tid];
    __syncthreads();

    if (tid < 256) {                     // KV: 8 partials per k (same order)
        int k = tid >> 3, p8 = tid & 7;
        float a = 0.f;
        #pragma unroll
        for (int g = p8 * 32; g < p8 * 32 + 32; ++g)
            a += gaf_s[g] * Wkv[k * GAF + g];
        kvp[k][p8] = a;
    }
    __syncthreads();
    if (tid < DKK) {
        float a = 0.f;
        #pragma unroll
        for (int p = 0; p < 8; ++p) a += kvp[tid][p];
        kv_s[tid] = a;
    }
    __syncthreads();

    int d0 = h * 256;
    if (tid < 256) {                     // u for this half's 256 d
        int d = d0 + tid;
        float uu = 0.f;
        #pragma unroll
        for (int k = 0; k < DKK; ++k) uu += kv_s[k] * Wout[d * DKK + k];
        uq_s[tid].x = uu;
        u[b * DTCF + d] = uu;
    } else if (tid < 512) {              // qv for this half's 256 d
        int d = d0 + tid - 256;
        float qq = 0.f;
        #pragma unroll
        for (int k = 0; k < DKK; ++k) qq += kv_s[k] * Wq[k * DTCF + d];
        uq_s[tid - 256].y = qq;
    }
    __syncthreads();

    // main stream: thread owns t = tid; 256 d ascending. 256B/wave-instr.
    const float* col = tcf + ((size_t)b * DTCF + d0) * TT + tid;
    float sx = 0.f, sxx = 0.f, sxu = 0.f, sxq = 0.f;
    #pragma unroll 16
    for (int d = 0; d < 256; ++d) {
        float v = col[(size_t)d << 10];
        float2 uq = uq_s[d];             // ds_read_b64 broadcast
        sx  += v;
        sxx += v * v;
        sxu += v * uq.x;
        sxq += v * uq.y;
    }

    float* p = part + (size_t)((b * 2 + h) * 4) * TT + tid;
    p[0]      = sx;
    p[TT]     = sxx;
    p[2 * TT] = sxu;
    p[3 * TT] = sxq;
}

// ---------------------------------------------------------------------------
// Kernel 2: combine halves + softmax over T + r_t + muu/S2/S3 per b.
// Blocks [BN, BN+8): W1 transpose (runs concurrently on idle CUs).
// ---------------------------------------------------------------------------
__global__ __launch_bounds__(256) void k_soft(
    const float* __restrict__ part, const float* __restrict__ u,
    const float* __restrict__ W1,
    float* __restrict__ muu, float* __restrict__ r_o,
    float* __restrict__ S2, float* __restrict__ S3, float* __restrict__ W1t)
{
    int bx = blockIdx.x, tid = threadIdx.x;

    if (bx >= BN) {                      // W1 transpose: 8 blocks x 4096 elems
        int e0 = (bx - BN) * 4096 + tid * 16;
        int j  = e0 >> 9;                // 16 elems stay within one source row
        int dd = e0 & 511;
        #pragma unroll
        for (int i = 0; i < 16; ++i)
            W1t[(dd + i) * HID + j] = W1[j * DTCF + dd + i];
        return;
    }

    int b = bx, lane = tid & 63, wv = tid >> 6;
    __shared__ float red[16];
    __shared__ float stats[2];

    // muu/varu from u[b,:]
    float su = 0.f, suu = 0.f;
    for (int i = tid; i < DTCF; i += 256) {
        float uu = u[b * DTCF + i];
        su += uu; suu += uu * uu;
    }
    #pragma unroll
    for (int off = 32; off > 0; off >>= 1) {
        su  += __shfl_down(su, off);
        suu += __shfl_down(suu, off);
    }
    if (lane == 0) { red[wv] = su; red[8 + wv] = suu; }
    __syncthreads();
    if (tid == 0) {
        float s  = red[0] + red[1] + red[2] + red[3];
        float ss = red[8] + red[9] + red[10] + red[11];
        float m = s * (1.f / DTCF);
        stats[0] = m;
        stats[1] = ss * (1.f / DTCF) - m * m;
        muu[b] = m;
    }
    __syncthreads();
    float mu = stats[0], vu = stats[1];

    int t0 = tid * 4;
    float4 sx = {0,0,0,0}, sxx = {0,0,0,0}, sxu = {0,0,0,0}, sxq = {0,0,0,0};
    #pragma unroll
    for (int h = 0; h < 2; ++h) {
        const float* p = part + (size_t)((b * 2 + h) * 4) * TT + t0;
        float4 a  = *(const float4*)(p);
        float4 bq = *(const float4*)(p + TT);
        float4 c  = *(const float4*)(p + 2 * TT);
        float4 dq = *(const float4*)(p + 3 * TT);
        sx.x  += a.x;  sx.y  += a.y;  sx.z  += a.z;  sx.w  += a.w;
        sxx.x += bq.x; sxx.y += bq.y; sxx.z += bq.z; sxx.w += bq.w;
        sxu.x += c.x;  sxu.y += c.y;  sxu.z += c.z;  sxu.w += c.w;
        sxq.x += dq.x; sxq.y += dq.y; sxq.z += dq.z; sxq.w += dq.w;
    }

    const float inv_d = 1.f / DTCF;
    float mx[4], vx[4], cv[4], sc[4];
    float sxa[4]  = {sx.x, sx.y, sx.z, sx.w};
    float sxxa[4] = {sxx.x, sxx.y, sxx.z, sxx.w};
    float sxua[4] = {sxu.x, sxu.y, sxu.z, sxu.w};
    float sxqa[4] = {sxq.x, sxq.y, sxq.z, sxq.w};
    #pragma unroll
    for (int i = 0; i < 4; ++i) {
        mx[i] = sxa[i] * inv_d;
        vx[i] = sxxa[i] * inv_d - mx[i] * mx[i];
        cv[i] = sxua[i] * inv_d - mx[i] * mu;
        sc[i] = sxqa[i] * SCALE;
    }

    float m = fmaxf(fmaxf(sc[0], sc[1]), fmaxf(sc[2], sc[3]));
    #pragma unroll
    for (int off = 32; off > 0; off >>= 1) m = fmaxf(m, __shfl_xor(m, off));
    __syncthreads();                     // red reuse guard
    if (lane == 0) red[wv] = m;
    __syncthreads();
    m = fmaxf(fmaxf(red[0], red[1]), fmaxf(red[2], red[3]));

    float e[4], sum = 0.f;
    #pragma unroll
    for (int i = 0; i < 4; ++i) { e[i] = __expf(sc[i] - m); sum += e[i]; }
    #pragma unroll
    for (int off = 32; off > 0; off >>= 1) sum += __shfl_xor(sum, off);
    if (lane == 0) red[4 + wv] = sum;
    __syncthreads();
    sum = red[4] + red[5] + red[6] + red[7];
    float inv = 1.f / sum;

    float rr4[4], s2a = 0.f, s3a = 0.f;
    #pragma unroll
    for (int i = 0; i < 4; ++i) {
        float w = e[i] * inv;
        float vr = vx[i] + 2.f * w * cv[i] + w * w * vu;
        float rr = rsqrtf(vr + LNEPS);
        rr4[i] = rr;
        s2a += rr * w;
        s3a += rr * mx[i];
    }
    *(float4*)(r_o + (size_t)b * TT + t0) = make_float4(rr4[0], rr4[1], rr4[2], rr4[3]);

    #pragma unroll
    for (int off = 32; off > 0; off >>= 1) {
        s2a += __shfl_xor(s2a, off);
        s3a += __shfl_xor(s3a, off);
    }
    if (lane == 0) { red[8 + wv] = s2a; red[12 + wv] = s3a; }
    __syncthreads();
    if (tid == 0) {
        S2[b] = (red[8] + red[9] + red[10] + red[11]) * (1.f / TT);
        S3[b] = (red[12] + red[13] + red[14] + red[15]) * (1.f / TT);
    }
}

// ---------------------------------------------------------------------------
// Kernel 3: pass B. One wave per (b,d) row: dot(r[b,:], tcf[b,d,:]).
// d mapped DESCENDING (most-recently-streamed rows of pass A first -> L3
// hits); tcf via nontemporal loads (last use, don't disturb LRU).
// ---------------------------------------------------------------------------
__global__ __launch_bounds__(256) void k_passB(
    const float* __restrict__ tcf, const float* __restrict__ r,
    const float* __restrict__ u, const float* __restrict__ muu,
    const float* __restrict__ S2, const float* __restrict__ S3,
    const float* __restrict__ g1, const float* __restrict__ be1,
    float* __restrict__ pooled)
{
    int b = blockIdx.x, yb = blockIdx.y;
    int tid = threadIdx.x, wv = tid >> 6, lane = tid & 63;
    int d = (DTCF - 4) - yb * 4 + wv;    // yb=0 -> d=508..511 (freshest in L3)

    const float* row = tcf + ((size_t)b * DTCF + d) * TT;
    const float* rb  = r + (size_t)b * TT;

    float acc = 0.f;
    #pragma unroll
    for (int i = 0; i < 4; ++i) {
        f4v    x  = __builtin_nontemporal_load((const f4v*)(row + i * 256 + lane * 4));
        float4 rv = *(const float4*)(rb + i * 256 + lane * 4);
        acc += rv.x * x.x + rv.y * x.y + rv.z * x.z + rv.w * x.w;
    }
    for (int off = 32; off > 0; off >>= 1) acc += __shfl_down(acc, off);

    if (lane == 0) {
        float pd = acc * (1.f / TT) - S3[b] + (u[b * DTCF + d] - muu[b]) * S2[b];
        pooled[b * DTCF + d] = g1[d] * pd + be1[d];
    }
}

// ---------------------------------------------------------------------------
// Kernel 4: head. Block = 4 waves; wave wv covers dd-chunk of 128, lane j owns
// hidden unit j via coalesced W1t reads. Wave 0 finishes LN2+ELU+classes.
// ---------------------------------------------------------------------------
__global__ __launch_bounds__(256) void k_head(
    const float* __restrict__ pooled, const float* __restrict__ W1t,
    const float* __restrict__ b1, const float* __restrict__ g2,
    const float* __restrict__ be2, const float* __restrict__ W2,
    const float* __restrict__ b2o, float* __restrict__ out)
{
    int b = blockIdx.x, tid = threadIdx.x;
    int j = tid & 63, wv = tid >> 6;
    __shared__ float p_s[DTCF];
    __shared__ float hred[4][HID];
    for (int i = tid; i < DTCF; i += 256) p_s[i] = pooled[b * DTCF + i];
    __syncthreads();

    float hp = 0.f;
    #pragma unroll 8
    for (int i = 0; i < 128; ++i) {
        int dd = wv * 128 + i;
        hp += p_s[dd] * W1t[dd * HID + j];
    }
    hred[wv][j] = hp;
    __syncthreads();

    if (wv == 0) {
        float h = hred[0][j] + hred[1][j] + hred[2][j] + hred[3][j] + b1[j];
        float mu = h;
        for (int off = 32; off > 0; off >>= 1) mu += __shfl_xor(mu, off);
        mu *= (1.f / HID);
        float df = h - mu;
        float vr = df * df;
        for (int off = 32; off > 0; off >>= 1) vr += __shfl_xor(vr, off);
        vr *= (1.f / HID);
        float hn = df * rsqrtf(vr + LNEPS) * g2[j] + be2[j];
        float he = hn > 0.f ? hn : expm1f(hn);

        #pragma unroll
        for (int c = 0; c < NCLS; ++c) {
            float v = he * W2[c * HID + j];
            for (int off = 32; off > 0; off >>= 1) v += __shfl_xor(v, off);
            if (j == 0) out[b * NCLS + c] = v + b2o[c];
        }
    }
}

extern "C" void kernel_launch(void* const* d_in, const int* in_sizes, int n_in,
                              void* d_out, int out_size, void* d_ws, size_t ws_size,
                              hipStream_t stream)
{
    const float* tcf  = (const float*)d_in[0];
    const float* gaf  = (const float*)d_in[1];
    const float* Wq   = (const float*)d_in[2];
    const float* Wkv  = (const float*)d_in[3];
    const float* Wout = (const float*)d_in[4];
    const float* ln1g = (const float*)d_in[5];
    const float* ln1b = (const float*)d_in[6];
    const float* W1   = (const float*)d_in[7];
    const float* b1   = (const float*)d_in[8];
    const float* ln2g = (const float*)d_in[9];
    const float* ln2b = (const float*)d_in[10];
    const float* W2   = (const float*)d_in[11];
    const float* b2   = (const float*)d_in[12];

    float* ws     = (float*)d_ws;
    float* u      = ws;                   // B*DTCF
    float* muu    = u + BN * DTCF;        // B
    float* r      = muu + BN;             // B*T
    float* S2     = r + BN * TT;          // B
    float* S3     = S2 + BN;              // B
    float* pooled = S3 + BN;              // B*DTCF
    float* W1t    = pooled + BN * DTCF;   // 512*64
    float* part   = W1t + DTCF * HID;     // B*2*4*T = 1M floats (4 MB)

    k_A<<<dim3(BN, 2), 1024, 0, stream>>>(tcf, gaf, Wq, Wkv, Wout, u, part);
    k_soft<<<BN + 8, 256, 0, stream>>>(part, u, W1, muu, r, S2, S3, W1t);
    k_passB<<<dim3(BN, DTCF / 4), 256, 0, stream>>>(tcf, r, u, muu, S2, S3,
                                                    ln1g, ln1b, pooled);
    k_head<<<BN, 256, 0, stream>>>(pooled, W1t, b1, ln2g, ln2b, W2, b2,
                                   (float*)d_out);
}